// Round 10
// baseline (909.237 us; speedup 1.0000x reference)
//
#include <hip/hip_runtime.h>
#include <stdint.h>

// SDFNetwork: instant-ngp hashgrid encode (L=16, F=2, T=2^19, base=16, scale=1.3819)
// + fully-fused MLP 32 -> 64 -> 64 -> 1 (bias-free, ReLU hidden, linear out), all fp32.
//
// Round 10 = round 9 resubmitted (GPU-acquisition timeout, never ran):
//  - encode: unchanged from round 8 (corner-pair gathers; ~400us, address-rate bound).
//  - MLP rewritten wave-transposed: lane j = neuron j, W0/W1 columns live in VGPRs
//    (one coalesced load per block, zero steady-state weight traffic -> kills the
//    s_load/sK$ stalls that held round-8's mlp2s at ~235us). enc broadcast from a
//    conflict-free LDS tile; h1 exchanged via wave-private LDS (no barriers);
//    layer-3 via 6-step shfl_xor butterfly.

#define NLVL 16
#define TBLSZ (1u << 19)
#define HID 64
#define ENCD 32
#define WPTS 256   // points per wave in mlp_wt

typedef float f32x4 __attribute__((ext_vector_type(4)));
typedef float f32x2 __attribute__((ext_vector_type(2)));

// res_l = floor(16 * 1.3819^l); levels 0..4 are dense ((res+1)^3 <= T), 5..15 hashed.
__device__ constexpr int RES[NLVL] = {16, 22, 30, 42, 58, 80, 111, 153, 212, 294,
                                      406, 561, 775, 1072, 1481, 2047};

struct Corner8 {
    uint32_t i[8];
    float w[8];
};

__device__ __forceinline__ void corner_idx(int l, float x01, float y01, float z01,
                                           Corner8& c)
{
    const int res = RES[l];
    const float fres = (float)res;
    const float px = x01 * fres, py = y01 * fres, pz = z01 * fres;
    const float fx = floorf(px), fy = floorf(py), fz = floorf(pz);
    const float tx = px - fx, ty = py - fy, tz = pz - fz;
    const uint32_t cx = (uint32_t)fx, cy = (uint32_t)fy, cz = (uint32_t)fz;

    if (l < 5) {
        const uint32_t s1 = (uint32_t)(res + 1);
        const uint32_t s2 = s1 * s1;
        const uint32_t bx0 = cx, bx1 = cx + 1u;
        const uint32_t by0 = cy * s1, by1 = by0 + s1;
        const uint32_t bz0 = cz * s2, bz1 = bz0 + s2;
        c.i[0] = bx0 + by0 + bz0; c.i[1] = bx0 + by0 + bz1;
        c.i[2] = bx0 + by1 + bz0; c.i[3] = bx0 + by1 + bz1;
        c.i[4] = bx1 + by0 + bz0; c.i[5] = bx1 + by0 + bz1;
        c.i[6] = bx1 + by1 + bz0; c.i[7] = bx1 + by1 + bz1;
    } else {
        const uint32_t P1 = 2654435761u, P2 = 805459861u;
        const uint32_t M = TBLSZ - 1u;
        const uint32_t hx0 = cx, hx1 = cx + 1u;
        const uint32_t hy0 = cy * P1, hy1 = hy0 + P1;
        const uint32_t hz0 = cz * P2, hz1 = hz0 + P2;
        c.i[0] = (hx0 ^ hy0 ^ hz0) & M; c.i[1] = (hx0 ^ hy0 ^ hz1) & M;
        c.i[2] = (hx0 ^ hy1 ^ hz0) & M; c.i[3] = (hx0 ^ hy1 ^ hz1) & M;
        c.i[4] = (hx1 ^ hy0 ^ hz0) & M; c.i[5] = (hx1 ^ hy0 ^ hz1) & M;
        c.i[6] = (hx1 ^ hy1 ^ hz0) & M; c.i[7] = (hx1 ^ hy1 ^ hz1) & M;
    }

    const float wx1 = tx, wx0 = 1.0f - tx;
    const float wy1 = ty, wy0 = 1.0f - ty;
    const float wz1 = tz, wz0 = 1.0f - tz;
    const float w00 = wx0 * wy0, w01 = wx0 * wy1;
    const float w10 = wx1 * wy0, w11 = wx1 * wy1;
    c.w[0] = w00 * wz0; c.w[1] = w00 * wz1;
    c.w[2] = w01 * wz0; c.w[3] = w01 * wz1;
    c.w[4] = w10 * wz0; c.w[5] = w10 * wz1;
    c.w[6] = w11 * wz0; c.w[7] = w11 * wz1;
}

// Gather the 8 corners; pairs (p, p+4) differ only in x. When their indices are
// bitwise-adjacent ((i0^i1)==1), one aligned 16B load fetches both corners.
__device__ __forceinline__ void gather8(const Corner8& c, const float2* __restrict__ tab,
                                        float2 f[8])
{
    #pragma unroll
    for (int p = 0; p < 4; ++p) {
        const uint32_t i0 = c.i[p], i1 = c.i[p + 4];
        if ((i0 ^ i1) == 1u) {
            const f32x4 q = *(const f32x4*)&tab[i0 & ~1u];   // 16B aligned
            if (i0 & 1u) {
                f[p]     = make_float2(q.z, q.w);
                f[p + 4] = make_float2(q.x, q.y);
            } else {
                f[p]     = make_float2(q.x, q.y);
                f[p + 4] = make_float2(q.z, q.w);
            }
        } else {
            f[p]     = tab[i0];
            f[p + 4] = tab[i1];
        }
    }
}

__device__ __forceinline__ void wsum8(const Corner8& c, const float2* __restrict__ f,
                                      float& e0, float& e1)
{
    e0 = c.w[0] * f[0].x;
    e1 = c.w[0] * f[0].y;
    #pragma unroll
    for (int k = 1; k < 8; ++k) {
        e0 = fmaf(c.w[k], f[k].x, e0);
        e1 = fmaf(c.w[k], f[k].y, e1);
    }
}

// ---------------- Kernel A: level-blocked encode, 2 points/thread ----------------
__global__ __launch_bounds__(256)
void encode_level2(const float* __restrict__ x,
                   const float* __restrict__ tables,
                   float2* __restrict__ enc, int npts)
{
    const int l = blockIdx.y;
    const int t = blockIdx.x * 256 + threadIdx.x;
    const int n0 = 2 * t;
    if (n0 >= npts) return;
    const bool has1 = (n0 + 1) < npts;

    const float2 a = *(const float2*)&x[6 * (size_t)t + 0];
    const float2 b = *(const float2*)&x[6 * (size_t)t + 2];
    const float2 c2 = has1 ? *(const float2*)&x[6 * (size_t)t + 4] : make_float2(0.f, 0.f);

    const float xA = (a.x + 1.0f) * 0.5f;
    const float yA = (a.y + 1.0f) * 0.5f;
    const float zA = (b.x + 1.0f) * 0.5f;
    const float xB = has1 ? (b.y + 1.0f) * 0.5f : xA;
    const float yB = has1 ? (c2.x + 1.0f) * 0.5f : yA;
    const float zB = has1 ? (c2.y + 1.0f) * 0.5f : zA;

    Corner8 A, B;
    corner_idx(l, xA, yA, zA, A);
    corner_idx(l, xB, yB, zB, B);

    const float2* tab = (const float2*)tables + (size_t)l * TBLSZ;
    float2 fA[8], fB[8];
    gather8(A, tab, fA);
    gather8(B, tab, fB);

    float eA0, eA1, eB0, eB1;
    wsum8(A, fA, eA0, eA1);
    wsum8(B, fB, eB0, eB1);

    const size_t base = (size_t)l * npts + n0;
    if (has1) {
        f32x4 v = {eA0, eA1, eB0, eB1};
        __builtin_nontemporal_store(v, (f32x4*)&enc[base]);
    } else {
        f32x2 v = {eA0, eA1};
        __builtin_nontemporal_store(v, (f32x2*)&enc[base]);
    }
}

// ---------------- Kernel B: wave-transposed MLP, weights in VGPRs ----------------
// Lane j = neuron j. W0 column j (32 VGPR), W1 column j (64 VGPR), W2[j] loaded
// once per block (coalesced). Per point: enc broadcast from LDS tile, layer-1 in
// lanes, h1 swapped through wave-private LDS (same-wave DS ops are in-order, no
// barrier), layer-2 in lanes, layer-3 shfl_xor butterfly; results collected one
// lane per point, stored coalesced per 64-point chunk.
__global__ __launch_bounds__(256)
void mlp_wt(const float2* __restrict__ enc,
            const float* __restrict__ W0,
            const float* __restrict__ W1,
            const float* __restrict__ W2,
            float* __restrict__ out, int npts)
{
    // 136B (34-float) point stride: bank = (2p + 2l) % 32 during staging -> spread;
    // compute reads are same-address broadcasts (conflict-free by definition).
    __shared__ float encT[4][64 * 34];
    __shared__ float h1T[4][64];

    const int tid  = threadIdx.x;
    const int w    = tid >> 6;
    const int lane = tid & 63;

    float w0c[ENCD], w1c[HID];
    #pragma unroll
    for (int i = 0; i < ENCD; ++i) w0c[i] = W0[i * HID + lane];
    #pragma unroll
    for (int j = 0; j < HID; ++j) w1c[j] = W1[j * HID + lane];
    const float w2c = W2[lane];

    float* encW = encT[w];
    float* h1W  = h1T[w];

    const int64_t wave_base = ((int64_t)blockIdx.x * 4 + w) * WPTS;

    #pragma unroll 1
    for (int c = 0; c < WPTS / 64; ++c) {
        const int64_t n0 = wave_base + (int64_t)c * 64;
        if (n0 >= npts) break;

        // stage enc[l][n0+lane] (coalesced 8B/lane) into the wave's LDS tile
        #pragma unroll 8
        for (int l = 0; l < NLVL; ++l) {
            f32x2 e = {0.0f, 0.0f};
            if (n0 + lane < npts)
                e = __builtin_nontemporal_load(
                        (const f32x2*)&enc[(size_t)l * npts + n0 + lane]);
            *(f32x2*)&encW[lane * 34 + 2 * l] = e;
        }

        float keep = 0.0f;
        #pragma unroll 1
        for (int p = 0; p < 64; ++p) {
            const float* ep = &encW[p * 34];
            // layer 1: h1_lane = sum_i enc[i] * W0[i][lane]
            float a0 = 0.0f, a1 = 0.0f;
            #pragma unroll
            for (int i = 0; i < ENCD; i += 4) {
                const f32x2 u = *(const f32x2*)&ep[i];
                const f32x2 v = *(const f32x2*)&ep[i + 2];
                a0 = fmaf(u.x, w0c[i + 0], a0);
                a1 = fmaf(u.y, w0c[i + 1], a1);
                a0 = fmaf(v.x, w0c[i + 2], a0);
                a1 = fmaf(v.y, w0c[i + 3], a1);
            }
            h1W[lane] = fmaxf(a0 + a1, 0.0f);
            // same-wave DS ordering makes the transpose visible without a barrier
            // layer 2: h2_lane = sum_j relu_h1[j] * W1[j][lane]
            float b0 = 0.0f, b1 = 0.0f, b2 = 0.0f, b3 = 0.0f;
            #pragma unroll
            for (int j = 0; j < HID; j += 4) {
                const f32x4 h = *(const f32x4*)&h1W[j];   // broadcast b128
                b0 = fmaf(h.x, w1c[j + 0], b0);
                b1 = fmaf(h.y, w1c[j + 1], b1);
                b2 = fmaf(h.z, w1c[j + 2], b2);
                b3 = fmaf(h.w, w1c[j + 3], b3);
            }
            const float h2 = (b0 + b1) + (b2 + b3);
            // layer 3: wave-sum of relu(h2)*W2[lane]
            float t = fmaxf(h2, 0.0f) * w2c;
            t += __shfl_xor(t, 32, 64);
            t += __shfl_xor(t, 16, 64);
            t += __shfl_xor(t, 8, 64);
            t += __shfl_xor(t, 4, 64);
            t += __shfl_xor(t, 2, 64);
            t += __shfl_xor(t, 1, 64);
            keep = (lane == p) ? t : keep;
        }

        if (n0 + lane < npts)
            out[n0 + lane] = keep;
    }
}

// ---------------- Fallback: fused kernel (if ws too small) ----------------
__global__ __launch_bounds__(256)
void sdf_fused(const float* __restrict__ x,
               const float* __restrict__ tables,
               const float* __restrict__ W0,
               const float* __restrict__ W1,
               const float* __restrict__ W2,
               float* __restrict__ out, int npts)
{
    __shared__ float sW0[ENCD * HID];
    __shared__ float sW1t[HID * HID];
    __shared__ float sW2[HID];

    const int tid = threadIdx.x;
    for (int idx = tid; idx < ENCD * HID; idx += 256) sW0[idx] = W0[idx];
    for (int idx = tid; idx < HID * HID; idx += 256) {
        const int j = idx >> 6, i = idx & 63;
        sW1t[idx] = W1[(i << 6) + j];
    }
    if (tid < HID) sW2[tid] = W2[tid];
    __syncthreads();

    const int n = blockIdx.x * 256 + tid;
    if (n >= npts) return;

    const float x01 = (x[3 * n + 0] + 1.0f) * 0.5f;
    const float y01 = (x[3 * n + 1] + 1.0f) * 0.5f;
    const float z01 = (x[3 * n + 2] + 1.0f) * 0.5f;

    float h1[HID];
    #pragma unroll
    for (int j = 0; j < HID; ++j) h1[j] = 0.0f;
    #pragma unroll
    for (int l = 0; l < NLVL; ++l) {
        Corner8 A;
        corner_idx(l, x01, y01, z01, A);
        const float2* tab = (const float2*)tables + (size_t)l * TBLSZ;
        float2 f[8];
        gather8(A, tab, f);
        float e0, e1;
        wsum8(A, f, e0, e1);
        const float* wr0 = &sW0[(2 * l) << 6];
        const float* wr1 = &sW0[(2 * l + 1) << 6];
        #pragma unroll
        for (int j = 0; j < HID; ++j)
            h1[j] = fmaf(e0, wr0[j], fmaf(e1, wr1[j], h1[j]));
    }
    #pragma unroll
    for (int j = 0; j < HID; ++j) h1[j] = fmaxf(h1[j], 0.0f);

    float acc = 0.0f;
    #pragma unroll
    for (int j = 0; j < HID; ++j) {
        const float* wr = &sW1t[j << 6];
        float t0 = 0.0f, t1 = 0.0f, t2 = 0.0f, t3 = 0.0f;
        #pragma unroll
        for (int i = 0; i < HID; i += 4) {
            t0 = fmaf(h1[i + 0], wr[i + 0], t0);
            t1 = fmaf(h1[i + 1], wr[i + 1], t1);
            t2 = fmaf(h1[i + 2], wr[i + 2], t2);
            t3 = fmaf(h1[i + 3], wr[i + 3], t3);
        }
        const float t = (t0 + t1) + (t2 + t3);
        acc = fmaf(fmaxf(t, 0.0f), sW2[j], acc);
    }
    out[n] = acc;
}

extern "C" void kernel_launch(void* const* d_in, const int* in_sizes, int n_in,
                              void* d_out, int out_size, void* d_ws, size_t ws_size,
                              hipStream_t stream) {
    const float* x      = (const float*)d_in[0];
    const float* tables = (const float*)d_in[1];
    const float* W0     = (const float*)d_in[2];
    const float* W1     = (const float*)d_in[3];
    const float* W2     = (const float*)d_in[4];
    float* out = (float*)d_out;

    const int npts = in_sizes[0] / 3;
    const size_t ws_needed = (size_t)NLVL * (size_t)npts * sizeof(float2);

    if (ws_size >= ws_needed) {
        float2* enc = (float2*)d_ws;
        const int npair = (npts + 1) / 2;
        dim3 egrid((npair + 255) / 256, NLVL);
        encode_level2<<<egrid, 256, 0, stream>>>(x, tables, enc, npts);
        const int pts_per_block = 4 * WPTS;
        const int mblocks = (npts + pts_per_block - 1) / pts_per_block;
        mlp_wt<<<mblocks, 256, 0, stream>>>(enc, W0, W1, W2, out, npts);
    } else {
        sdf_fused<<<(npts + 255) / 256, 256, 0, stream>>>(x, tables, W0, W1, W2, out, npts);
    }
}

// Round 13
// 710.204 us; speedup vs baseline: 1.2802x; 1.2802x over previous
//
#include <hip/hip_runtime.h>
#include <stdint.h>

// SDFNetwork: instant-ngp hashgrid encode (L=16, F=2, T=2^19, base=16, scale=1.3819)
// + fully-fused MLP 32 -> 64 -> 64 -> 1 (bias-free, ReLU hidden, linear out), all fp32.
//
// Round 13 = round 11/12 resubmitted (container infra failures, never ran):
//  - encode: TCP processes ~1 lane-address/cycle/CU (r7->r8 scaling). Dense levels
//    always have i1==i0+1 -> branchless single 16B load per x-pair (8B-aligned OK),
//    cutting dense addresses 6->4 per pt-level (96->86 total, -10%).
//  - MLP: r8 mlp2s + __syncthreads() per jb-quarter to phase-lock the block's 4
//    waves on one 6KB weight quarter (fits 16KB sK$ -> inter-wave K$ hits), and
//    unroll-4 enc-level loop (multiple enc loads in flight).

#define NLVL 16
#define TBLSZ (1u << 19)
#define HID 64
#define ENCD 32

typedef float f32x4 __attribute__((ext_vector_type(4)));
typedef float f32x2 __attribute__((ext_vector_type(2)));
// 8B-aligned 16B vector for the always-pair dense load (tab is float2-aligned)
typedef float f32x4u __attribute__((ext_vector_type(4), aligned(8)));

// res_l = floor(16 * 1.3819^l); levels 0..4 are dense ((res+1)^3 <= T), 5..15 hashed.
__device__ constexpr int RES[NLVL] = {16, 22, 30, 42, 58, 80, 111, 153, 212, 294,
                                      406, 561, 775, 1072, 1481, 2047};

struct Corner8 {
    uint32_t i[8];
    float w[8];
};

__device__ __forceinline__ void corner_idx(int l, float x01, float y01, float z01,
                                           Corner8& c)
{
    const int res = RES[l];
    const float fres = (float)res;
    const float px = x01 * fres, py = y01 * fres, pz = z01 * fres;
    const float fx = floorf(px), fy = floorf(py), fz = floorf(pz);
    const float tx = px - fx, ty = py - fy, tz = pz - fz;
    const uint32_t cx = (uint32_t)fx, cy = (uint32_t)fy, cz = (uint32_t)fz;

    if (l < 5) {
        const uint32_t s1 = (uint32_t)(res + 1);
        const uint32_t s2 = s1 * s1;
        const uint32_t bx0 = cx, bx1 = cx + 1u;
        const uint32_t by0 = cy * s1, by1 = by0 + s1;
        const uint32_t bz0 = cz * s2, bz1 = bz0 + s2;
        c.i[0] = bx0 + by0 + bz0; c.i[1] = bx0 + by0 + bz1;
        c.i[2] = bx0 + by1 + bz0; c.i[3] = bx0 + by1 + bz1;
        c.i[4] = bx1 + by0 + bz0; c.i[5] = bx1 + by0 + bz1;
        c.i[6] = bx1 + by1 + bz0; c.i[7] = bx1 + by1 + bz1;
    } else {
        const uint32_t P1 = 2654435761u, P2 = 805459861u;
        const uint32_t M = TBLSZ - 1u;
        const uint32_t hx0 = cx, hx1 = cx + 1u;
        const uint32_t hy0 = cy * P1, hy1 = hy0 + P1;
        const uint32_t hz0 = cz * P2, hz1 = hz0 + P2;
        c.i[0] = (hx0 ^ hy0 ^ hz0) & M; c.i[1] = (hx0 ^ hy0 ^ hz1) & M;
        c.i[2] = (hx0 ^ hy1 ^ hz0) & M; c.i[3] = (hx0 ^ hy1 ^ hz1) & M;
        c.i[4] = (hx1 ^ hy0 ^ hz0) & M; c.i[5] = (hx1 ^ hy0 ^ hz1) & M;
        c.i[6] = (hx1 ^ hy1 ^ hz0) & M; c.i[7] = (hx1 ^ hy1 ^ hz1) & M;
    }

    const float wx1 = tx, wx0 = 1.0f - tx;
    const float wy1 = ty, wy0 = 1.0f - ty;
    const float wz1 = tz, wz0 = 1.0f - tz;
    const float w00 = wx0 * wy0, w01 = wx0 * wy1;
    const float w10 = wx1 * wy0, w11 = wx1 * wy1;
    c.w[0] = w00 * wz0; c.w[1] = w00 * wz1;
    c.w[2] = w01 * wz0; c.w[3] = w01 * wz1;
    c.w[4] = w10 * wz0; c.w[5] = w10 * wz1;
    c.w[6] = w11 * wz0; c.w[7] = w11 * wz1;
}

// Gather the 8 corners; pairs (p, p+4) differ only in x.
// dense: i[p+4] == i[p]+1 always -> ONE 16B load (8B-aligned), branchless.
// hashed: adjacent only when (i0^i1)==1 (cx even) -> aligned 16B load, else 2 loads.
__device__ __forceinline__ void gather8(const Corner8& c, const float2* __restrict__ tab,
                                        float2 f[8], bool dense)
{
    #pragma unroll
    for (int p = 0; p < 4; ++p) {
        const uint32_t i0 = c.i[p], i1 = c.i[p + 4];
        if (dense) {
            const f32x4u q = *(const f32x4u*)&tab[i0];   // i0, i0+1
            f[p]     = make_float2(q.x, q.y);
            f[p + 4] = make_float2(q.z, q.w);
        } else if ((i0 ^ i1) == 1u) {
            const f32x4 q = *(const f32x4*)&tab[i0 & ~1u];   // 16B aligned
            if (i0 & 1u) {
                f[p]     = make_float2(q.z, q.w);
                f[p + 4] = make_float2(q.x, q.y);
            } else {
                f[p]     = make_float2(q.x, q.y);
                f[p + 4] = make_float2(q.z, q.w);
            }
        } else {
            f[p]     = tab[i0];
            f[p + 4] = tab[i1];
        }
    }
}

__device__ __forceinline__ void wsum8(const Corner8& c, const float2* __restrict__ f,
                                      float& e0, float& e1)
{
    e0 = c.w[0] * f[0].x;
    e1 = c.w[0] * f[0].y;
    #pragma unroll
    for (int k = 1; k < 8; ++k) {
        e0 = fmaf(c.w[k], f[k].x, e0);
        e1 = fmaf(c.w[k], f[k].y, e1);
    }
}

// ---------------- Kernel A: level-blocked encode, 2 points/thread ----------------
// blockIdx.y = level; x-fastest dispatch keeps all resident blocks on ~one level,
// so that level's <=4MB table stays in the per-XCD L2.
__global__ __launch_bounds__(256)
void encode_level2(const float* __restrict__ x,
                   const float* __restrict__ tables,
                   float2* __restrict__ enc, int npts)
{
    const int l = blockIdx.y;
    const int t = blockIdx.x * 256 + threadIdx.x;
    const int n0 = 2 * t;
    if (n0 >= npts) return;
    const bool has1 = (n0 + 1) < npts;
    const bool dense = (l < 5);

    const float2 a = *(const float2*)&x[6 * (size_t)t + 0];
    const float2 b = *(const float2*)&x[6 * (size_t)t + 2];
    const float2 c2 = has1 ? *(const float2*)&x[6 * (size_t)t + 4] : make_float2(0.f, 0.f);

    const float xA = (a.x + 1.0f) * 0.5f;
    const float yA = (a.y + 1.0f) * 0.5f;
    const float zA = (b.x + 1.0f) * 0.5f;
    const float xB = has1 ? (b.y + 1.0f) * 0.5f : xA;
    const float yB = has1 ? (c2.x + 1.0f) * 0.5f : yA;
    const float zB = has1 ? (c2.y + 1.0f) * 0.5f : zA;

    Corner8 A, B;
    corner_idx(l, xA, yA, zA, A);
    corner_idx(l, xB, yB, zB, B);

    const float2* tab = (const float2*)tables + (size_t)l * TBLSZ;
    float2 fA[8], fB[8];
    gather8(A, tab, fA, dense);
    gather8(B, tab, fB, dense);

    float eA0, eA1, eB0, eB1;
    wsum8(A, fA, eA0, eA1);
    wsum8(B, fB, eB0, eB1);

    const size_t base = (size_t)l * npts + n0;
    if (has1) {
        f32x4 v = {eA0, eA1, eB0, eB1};
        __builtin_nontemporal_store(v, (f32x4*)&enc[base]);
    } else {
        f32x2 v = {eA0, eA1};
        __builtin_nontemporal_store(v, (f32x2*)&enc[base]);
    }
}

// ---------------- Kernel B: MLP 32 -> 64 -> 64 -> 1, 2 pts/thread, SGPR weights --
// Weight addresses are wave-uniform -> s_load into SGPRs; v_fma uses the SGPR
// operand. No LDS for weights. Layer 2 in j-quarters (h2=16/pt) caps live VGPRs.
// __syncthreads() per quarter phase-locks the block's 4 waves on one ~6KB weight
// quarter -> fits the 16KB per-CU sK$ -> the other 3 waves hit K$ instead of L2.
__global__ __launch_bounds__(256)
void mlp2p(const float2* __restrict__ enc,
           const float* __restrict__ W0,
           const float* __restrict__ W1,
           const float* __restrict__ W2,
           float* __restrict__ out, int npts)
{
    const int t = blockIdx.x * 256 + threadIdx.x;
    const int n0 = 2 * t;
    const bool active = n0 < npts;
    const bool has1 = (n0 + 1) < npts;

    float h1a[HID], h1b[HID];
    #pragma unroll
    for (int j = 0; j < HID; ++j) { h1a[j] = 0.0f; h1b[j] = 0.0f; }

    #pragma unroll 4
    for (int l = 0; l < NLVL; ++l) {
        f32x4 e = {0.0f, 0.0f, 0.0f, 0.0f};
        if (active) {
            if (has1) {
                e = __builtin_nontemporal_load((const f32x4*)&enc[(size_t)l * npts + n0]);
            } else {
                const f32x2 ea = __builtin_nontemporal_load(
                    (const f32x2*)&enc[(size_t)l * npts + n0]);
                e.x = ea.x; e.y = ea.y; e.z = ea.x; e.w = ea.y;
            }
        }
        #pragma unroll
        for (int j4 = 0; j4 < HID / 4; ++j4) {
            const f32x4 w0 = *(const f32x4*)&W0[(2 * l) * HID + 4 * j4];
            const f32x4 w1 = *(const f32x4*)&W0[(2 * l + 1) * HID + 4 * j4];
            #pragma unroll
            for (int k = 0; k < 4; ++k) {
                h1a[4 * j4 + k] = fmaf(e.x, w0[k], fmaf(e.y, w1[k], h1a[4 * j4 + k]));
                h1b[4 * j4 + k] = fmaf(e.z, w0[k], fmaf(e.w, w1[k], h1b[4 * j4 + k]));
            }
        }
    }

    // relu in place (reused across all 4 j-blocks)
    #pragma unroll
    for (int j = 0; j < HID; ++j) {
        h1a[j] = fmaxf(h1a[j], 0.0f);
        h1b[j] = fmaxf(h1b[j], 0.0f);
    }

    float accA = 0.0f, accB = 0.0f;
    #pragma unroll 1
    for (int jb = 0; jb < 4; ++jb) {
        __syncthreads();   // phase-lock all waves of the block on this quarter
        float h2a[HID / 4], h2b[HID / 4];
        #pragma unroll
        for (int j = 0; j < HID / 4; ++j) { h2a[j] = 0.0f; h2b[j] = 0.0f; }

        #pragma unroll
        for (int i = 0; i < HID; ++i) {
            const float ra = h1a[i], rb = h1b[i];
            const float* wrow = &W1[i * HID + jb * (HID / 4)];
            #pragma unroll
            for (int j4 = 0; j4 < HID / 16; ++j4) {
                const f32x4 w = *(const f32x4*)&wrow[4 * j4];
                #pragma unroll
                for (int k = 0; k < 4; ++k) {
                    h2a[4 * j4 + k] = fmaf(ra, w[k], h2a[4 * j4 + k]);
                    h2b[4 * j4 + k] = fmaf(rb, w[k], h2b[4 * j4 + k]);
                }
            }
        }

        #pragma unroll
        for (int j4 = 0; j4 < HID / 16; ++j4) {
            const f32x4 w = *(const f32x4*)&W2[jb * (HID / 4) + 4 * j4];
            #pragma unroll
            for (int k = 0; k < 4; ++k) {
                accA = fmaf(fmaxf(h2a[4 * j4 + k], 0.0f), w[k], accA);
                accB = fmaf(fmaxf(h2b[4 * j4 + k], 0.0f), w[k], accB);
            }
        }
    }

    if (active) out[n0] = accA;
    if (has1) out[n0 + 1] = accB;
}

// ---------------- Fallback: fused kernel (if ws too small) ----------------
__global__ __launch_bounds__(256)
void sdf_fused(const float* __restrict__ x,
               const float* __restrict__ tables,
               const float* __restrict__ W0,
               const float* __restrict__ W1,
               const float* __restrict__ W2,
               float* __restrict__ out, int npts)
{
    __shared__ float sW0[ENCD * HID];
    __shared__ float sW1t[HID * HID];
    __shared__ float sW2[HID];

    const int tid = threadIdx.x;
    for (int idx = tid; idx < ENCD * HID; idx += 256) sW0[idx] = W0[idx];
    for (int idx = tid; idx < HID * HID; idx += 256) {
        const int j = idx >> 6, i = idx & 63;
        sW1t[idx] = W1[(i << 6) + j];
    }
    if (tid < HID) sW2[tid] = W2[tid];
    __syncthreads();

    const int n = blockIdx.x * 256 + tid;
    if (n >= npts) return;

    const float x01 = (x[3 * n + 0] + 1.0f) * 0.5f;
    const float y01 = (x[3 * n + 1] + 1.0f) * 0.5f;
    const float z01 = (x[3 * n + 2] + 1.0f) * 0.5f;

    float h1[HID];
    #pragma unroll
    for (int j = 0; j < HID; ++j) h1[j] = 0.0f;
    #pragma unroll
    for (int l = 0; l < NLVL; ++l) {
        Corner8 A;
        corner_idx(l, x01, y01, z01, A);
        const float2* tab = (const float2*)tables + (size_t)l * TBLSZ;
        float2 f[8];
        gather8(A, tab, f, l < 5);
        float e0, e1;
        wsum8(A, f, e0, e1);
        const float* wr0 = &sW0[(2 * l) << 6];
        const float* wr1 = &sW0[(2 * l + 1) << 6];
        #pragma unroll
        for (int j = 0; j < HID; ++j)
            h1[j] = fmaf(e0, wr0[j], fmaf(e1, wr1[j], h1[j]));
    }
    #pragma unroll
    for (int j = 0; j < HID; ++j) h1[j] = fmaxf(h1[j], 0.0f);

    float acc = 0.0f;
    #pragma unroll
    for (int j = 0; j < HID; ++j) {
        const float* wr = &sW1t[j << 6];
        float t0 = 0.0f, t1 = 0.0f, t2 = 0.0f, t3 = 0.0f;
        #pragma unroll
        for (int i = 0; i < HID; i += 4) {
            t0 = fmaf(h1[i + 0], wr[i + 0], t0);
            t1 = fmaf(h1[i + 1], wr[i + 1], t1);
            t2 = fmaf(h1[i + 2], wr[i + 2], t2);
            t3 = fmaf(h1[i + 3], wr[i + 3], t3);
        }
        const float t = (t0 + t1) + (t2 + t3);
        acc = fmaf(fmaxf(t, 0.0f), sW2[j], acc);
    }
    out[n] = acc;
}

extern "C" void kernel_launch(void* const* d_in, const int* in_sizes, int n_in,
                              void* d_out, int out_size, void* d_ws, size_t ws_size,
                              hipStream_t stream) {
    const float* x      = (const float*)d_in[0];
    const float* tables = (const float*)d_in[1];
    const float* W0     = (const float*)d_in[2];
    const float* W1     = (const float*)d_in[3];
    const float* W2     = (const float*)d_in[4];
    float* out = (float*)d_out;

    const int npts = in_sizes[0] / 3;
    const size_t ws_needed = (size_t)NLVL * (size_t)npts * sizeof(float2);

    if (ws_size >= ws_needed) {
        float2* enc = (float2*)d_ws;
        const int npair = (npts + 1) / 2;
        dim3 egrid((npair + 255) / 256, NLVL);
        encode_level2<<<egrid, 256, 0, stream>>>(x, tables, enc, npts);
        mlp2p<<<(npair + 255) / 256, 256, 0, stream>>>(enc, W0, W1, W2, out, npts);
    } else {
        sdf_fused<<<(npts + 255) / 256, 256, 0, stream>>>(x, tables, W0, W1, W2, out, npts);
    }
}